// Round 1
// baseline (227.068 us; speedup 1.0000x reference)
//
#include <hip/hip_runtime.h>

// Performer (FAVOR+) self-attention. B=4 H=8 N=8192 D=64 M=256.
// Round 11: kCtx redesigned in the kOut structure.
//  - 512 blocks (8 tiles x 2 m-halves x 32 bh), 512 threads, ~75 KB LDS
//    -> 2 blocks/CU (launch_bounds(512,4) caps VGPR at 128).
//  - Wave-private p1: each wave owns 16 K rows, hi/lo f16 A-frags built in
//    registers from global (no A-stage through LDS); next-chunk K prefetched
//    into registers before p1. 2 barriers/chunk (was 4).
//  - Fs stride 140 + b64 A-frag reads: p2 bank conflicts 8-way -> ~2-way.
//  - Per-block maxes packed into tail of ksumG region (read-then-overwrite
//    in kRedCtx) so workspace total is unchanged.
// kPrep -> kCtx -> kRedCtx -> kOut

typedef __attribute__((ext_vector_type(8))) short short8;
typedef __attribute__((ext_vector_type(8))) _Float16 half8;
typedef __attribute__((ext_vector_type(4))) float f32x4;

namespace {
constexpr int BN = 8192, DD = 64, MM = 256, NHEADS = 32;
constexpr float CNORM = 0.35355339059327373f;  // D^-0.25
constexpr float FEPS  = 1e-4f;
constexpr float INV2048 = 4.8828125e-4f;

// workspace layout in floats (total 4,555,008 f = 18.22 MB, unchanged)
constexpr size_t OFF_BX    = 0;         // 16384 ushort = 8192 f
constexpr size_t OFF_CS    = 8192;      // 32*16384 ushort -> ends 270336
constexpr size_t OFF_KSUMP = 270336;    // 32*16*128 = 65536 -> 335872
constexpr size_t OFF_KSUMG = 335872;    // 32*256 = 8192 -> 344064 (mx packed @ +240..255/bh)
constexpr size_t OFF_VSP   = 344320;    // 32*8*64 = 16384 -> 360704 (hole 344064..344320 unused)
constexpr size_t OFF_CTXP  = 360704;    // 32*16*8192 = 4194304 -> 4555008
}

__device__ __forceinline__ unsigned short f2bf(float f) {
  unsigned u = __float_as_uint(f);
  u += 0x7fffu + ((u >> 16) & 1u);
  return (unsigned short)(u >> 16);
}
__device__ __forceinline__ float bf2f(unsigned short h) {
  return __uint_as_float(((unsigned)h) << 16);
}
__device__ __forceinline__ unsigned pk2(unsigned short a, unsigned short b) {
  return (unsigned)a | ((unsigned)b << 16);
}
__device__ __forceinline__ unsigned short f2h(float f) {
  _Float16 h = (_Float16)f;
  return __builtin_bit_cast(unsigned short, h);
}
__device__ __forceinline__ float h2f(unsigned short u) {
  return (float)__builtin_bit_cast(_Float16, u);
}

// XCD swizzle: linear id -> (bh, tile); each XCD owns 4 consecutive heads.
template <int T>
__device__ __forceinline__ void xcd_map(int& bh, int& tile) {
  int id = blockIdx.y * T + blockIdx.x;
  int xcd = id & 7, s = id >> 3;
  bh = xcd * 4 + s / T;
  tile = s % T;
}

// ---------------- kPrep: proj -> single-f16 B-fragment stream (32 KB) ----------------
// BxG[mt 16][kb 2][lane 64][8 f16]; kb = K-half (d 0-31 / 32-63).
__global__ void kPrep(const float* __restrict__ proj, unsigned short* __restrict__ BxG) {
  int s = blockIdx.x * 256 + threadIdx.x;   // 0..2047
  int l = s & 63, kb = (s >> 6) & 1, mt = s >> 7;
  int n = mt * 16 + (l & 15);
  int k0 = kb * 32 + (l >> 4) * 8;
  unsigned short o[8];
#pragma unroll
  for (int j = 0; j < 8; ++j) o[j] = f2h(proj[n * 64 + k0 + j]);
  *(uint4*)(BxG + (size_t)s * 8) =
      make_uint4(pk2(o[0], o[1]), pk2(o[2], o[3]), pk2(o[4], o[5]), pk2(o[6], o[7]));
}

// ---------------- kCtx: wave-private k-feature pipeline -> ctx/ksum partials ----------------
// Block = (bh, tile, mh): 1024 rows (8 chunks x 128), m-half mh*128..+128.
// Per chunk: wave w owns rows w*16 (A-frags in regs from global K), computes
// xd for its rows x 128 m; online block max; features transposed into Fs[m][n];
// p2: ctx[m][d] += k'^T V. 2 barriers/chunk.
__global__ void __launch_bounds__(512, 4)
kCtx(const float* __restrict__ Kin, const float* __restrict__ Vin,
     const float* __restrict__ mask, const unsigned short* __restrict__ BxG,
     float* __restrict__ ctxp, float* __restrict__ ksump,
     float* __restrict__ mxg, float* __restrict__ vsp) {
  __shared__ __align__(16) unsigned short BxH[8192];      // 16 KB (this m-half of proj)
  __shared__ __align__(16) unsigned short Fs[128 * 140];  // 35 KB features [m][n], stride 140
  __shared__ __align__(16) unsigned short VF[16 * 64 * 8];// 16 KB [ks4][dt4][lane64][8] bf16
  __shared__ float msks[128];
  __shared__ float wmax[8];
  __shared__ float ksred[1024];
  __shared__ float vred[512];
  const int tid = threadIdx.x;
  int bh, tl16;
  xcd_map<16>(bh, tl16);
  const int tile = tl16 >> 1, mh = tl16 & 1;
  const int b = bh >> 3;
  const float* Kh = Kin + (size_t)bh * BN * DD;
  const float* Vh = Vin + (size_t)bh * BN * DD;
  const float* mrow = mask + (size_t)b * BN;
#pragma unroll
  for (int i = 0; i < 2; ++i)
    ((uint4*)BxH)[tid + i * 512] = ((const uint4*)BxG)[mh * 1024 + tid + i * 512];
  const int w = tid >> 6, l = tid & 63, lm = l & 15, kl = l >> 4;
  const int lmv = tid & 15, klnv = (tid >> 4) & 3, dtv = (tid >> 6) & 3, ksv0 = tid >> 8;

  f32x4 cacc[4];
#pragma unroll
  for (int dt = 0; dt < 4; ++dt) cacc[dt] = f32x4{0.f, 0.f, 0.f, 0.f};
  float kspart[8] = {0.f, 0.f, 0.f, 0.f, 0.f, 0.f, 0.f, 0.f};
  float m_run = -3e38f, vsum = 0.f;

  const int rbase = tile * 1024;
  // peel: K regs for chunk 0
  float4 kv0, kv1, kv2, kv3;
  float mskK;
  {
    const float* rp = Kh + (size_t)(rbase + w * 16 + lm) * 64 + kl * 8;
    kv0 = *(const float4*)rp;        kv1 = *(const float4*)(rp + 4);
    kv2 = *(const float4*)(rp + 32); kv3 = *(const float4*)(rp + 36);
    mskK = mrow[rbase + w * 16 + lm];
  }
  __syncthreads();   // BxH ready

  for (int ch = 0; ch < 8; ++ch) {
    const int r0 = rbase + ch * 128;
    // ---- convert own K row regs -> hi/lo f16 A-frags + diag ----
    half8 ah0, ah1, al0, al1;
    float diagv;
    {
      float scale = CNORM * mskK;
      float x[16] = {kv0.x, kv0.y, kv0.z, kv0.w, kv1.x, kv1.y, kv1.z, kv1.w,
                     kv2.x, kv2.y, kv2.z, kv2.w, kv3.x, kv3.y, kv3.z, kv3.w};
      float sq = 0.f;
#pragma unroll
      for (int e = 0; e < 16; ++e) {
        float y = x[e] * scale;
        _Float16 h = (_Float16)y;
        _Float16 lo = (_Float16)((y - (float)h) * 2048.0f);
        if (e < 8) { ah0[e] = h; al0[e] = lo; } else { ah1[e - 8] = h; al1[e - 8] = lo; }
        sq = fmaf(y, y, sq);
      }
      sq += __shfl_xor(sq, 16);
      sq += __shfl_xor(sq, 32);
      diagv = 0.5f * sq;
    }
    // ---- prefetch next chunk's K rows (latency hides under p1..barrier2) ----
    {
      const int nr = rbase + ((ch + 1) & 7) * 128 + w * 16 + lm;
      const float* rp = Kh + (size_t)nr * 64 + kl * 8;
      kv0 = *(const float4*)rp;        kv1 = *(const float4*)(rp + 4);
      kv2 = *(const float4*)(rp + 32); kv3 = *(const float4*)(rp + 36);
      mskK = mrow[nr];
    }
    // ---- p1: xd for own 16 rows x 128 m (this half) ----
    f32x4 accC[8];
#pragma unroll
    for (int j = 0; j < 8; ++j) {
      half8 b0 = *(const half8*)&BxH[((j * 2 + 0) * 64 + l) * 8];
      half8 b1 = *(const half8*)&BxH[((j * 2 + 1) * 64 + l) * 8];
      f32x4 a0 = {0.f, 0.f, 0.f, 0.f}, a1 = {0.f, 0.f, 0.f, 0.f};
      a0 = __builtin_amdgcn_mfma_f32_16x16x32_f16(ah0, b0, a0, 0, 0, 0);
      a0 = __builtin_amdgcn_mfma_f32_16x16x32_f16(ah1, b1, a0, 0, 0, 0);
      a1 = __builtin_amdgcn_mfma_f32_16x16x32_f16(al0, b0, a1, 0, 0, 0);
      a1 = __builtin_amdgcn_mfma_f32_16x16x32_f16(al1, b1, a1, 0, 0, 0);
#pragma unroll
      for (int r = 0; r < 4; ++r) accC[j][r] = fmaf(a1[r], INV2048, a0[r]);
    }
    // ---- V loads for this chunk (consumed after barrier 1) ----
    float vv[16];
#pragma unroll
    for (int h = 0; h < 2; ++h) {
      int nb = (ksv0 * 2 + h) * 32 + klnv * 8;
#pragma unroll
      for (int j = 0; j < 8; ++j)
        vv[h * 8 + j] = Vh[(size_t)(r0 + nb + j) * 64 + dtv * 16 + lmv];
    }
    if (tid < 128) msks[tid] = mrow[r0 + tid];
    // ---- wave max of this chunk's xd ----
    {
      float wm = accC[0][0];
#pragma unroll
      for (int j = 0; j < 8; ++j)
#pragma unroll
        for (int r = 0; r < 4; ++r) wm = fmaxf(wm, accC[j][r]);
      wm = fmaxf(wm, __shfl_xor(wm, 1));  wm = fmaxf(wm, __shfl_xor(wm, 2));
      wm = fmaxf(wm, __shfl_xor(wm, 4));  wm = fmaxf(wm, __shfl_xor(wm, 8));
      wm = fmaxf(wm, __shfl_xor(wm, 16)); wm = fmaxf(wm, __shfl_xor(wm, 32));
      if (l == 0) wmax[w] = wm;
    }
    __syncthreads();   // barrier 1: wmax/msks ready, prev p2 reads done
    // ---- online max update: rescale running partials ----
    {
      float mxc = m_run;
#pragma unroll
      for (int i = 0; i < 8; ++i) mxc = fmaxf(mxc, wmax[i]);
      float fsc = __expf(m_run - mxc);
      m_run = mxc;
#pragma unroll
      for (int dt = 0; dt < 4; ++dt) cacc[dt] = cacc[dt] * fsc;
#pragma unroll
      for (int j = 0; j < 8; ++j) kspart[j] *= fsc;
    }
    // ---- V -> VF (bf16 frag-linear) + masked V row-sum ----
#pragma unroll
    for (int h = 0; h < 2; ++h) {
      int ks = ksv0 * 2 + h;
      int nb = ks * 32 + klnv * 8;
      unsigned short o[8];
#pragma unroll
      for (int j = 0; j < 8; ++j) {
        float vm = vv[h * 8 + j] * msks[nb + j];
        o[j] = f2bf(vm);
        vsum += vm;
      }
      *(uint4*)&VF[((ks * 4 + dtv) * 64 + klnv * 16 + lmv) * 8] =
          make_uint4(pk2(o[0], o[1]), pk2(o[2], o[3]), pk2(o[4], o[5]), pk2(o[6], o[7]));
    }
    // ---- features: k' = exp(xd - diag - m_run) -> Fs[m][n] (transposed) ----
    {
      float dgv[4];
#pragma unroll
      for (int r = 0; r < 4; ++r)
        dgv[r] = __shfl(diagv, (l & 48) + kl * 4 + r) + m_run;
#pragma unroll
      for (int j = 0; j < 8; ++j) {
        float f0 = __expf(accC[j][0] - dgv[0]);
        float f1 = __expf(accC[j][1] - dgv[1]);
        float f2 = __expf(accC[j][2] - dgv[2]);
        float f3 = __expf(accC[j][3] - dgv[3]);
        kspart[j] += f0 + f1 + f2 + f3;
        *(uint2*)&Fs[(j * 16 + lm) * 140 + w * 16 + kl * 4] =
            make_uint2(pk2(f2bf(f0), f2bf(f1)), pk2(f2bf(f2), f2bf(f3)));
      }
    }
    __syncthreads();   // barrier 2: Fs + VF ready
    // ---- p2: ctx[m][d] += k'^T V; wave w owns m-rows w*16..+16 ----
#pragma unroll
    for (int ks = 0; ks < 4; ++ks) {
      union { short8 v; uint2 u[2]; } af;
      const int ab = (w * 16 + lm) * 140 + ks * 32 + kl * 8;
      af.u[0] = *(const uint2*)&Fs[ab];
      af.u[1] = *(const uint2*)&Fs[ab + 4];
#pragma unroll
      for (int dt = 0; dt < 4; ++dt) {
        short8 vb = *(const short8*)&VF[((ks * 4 + dt) * 64 + l) * 8];
        cacc[dt] = __builtin_amdgcn_mfma_f32_16x16x32_bf16(af.v, vb, cacc[dt], 0, 0, 0);
      }
    }
  }
  // ---- epilogue: ksum partials, vsum, max, ctx partials ----
#pragma unroll
  for (int j = 0; j < 8; ++j) {
    kspart[j] += __shfl_xor(kspart[j], 16);
    kspart[j] += __shfl_xor(kspart[j], 32);
  }
  if (l < 16) {
#pragma unroll
    for (int j = 0; j < 8; ++j) ksred[(j * 16 + l) * 8 + w] = kspart[j];
  }
  vred[tid] = vsum;
  __syncthreads();
  if (tid < 128) {
    float s = 0.f;
#pragma unroll
    for (int k = 0; k < 8; ++k) s += ksred[tid * 8 + k];
    ksump[(size_t)(bh * 16 + tl16) * 128 + tid] = s;
  }
  if (mh == 0 && tid < 64) {
    float vs = 0.f;
#pragma unroll
    for (int k = 0; k < 8; ++k)
      vs += vred[(k >> 2) * 256 + (tid >> 4) * 64 + (k & 3) * 16 + (tid & 15)];
    vsp[(size_t)(bh * 8 + tile) * 64 + tid] = vs;
  }
  if (tid == 0) mxg[bh * 256 + 240 + tl16] = m_run;   // packed into ksumG tail
  float* cp = ctxp + (size_t)(bh * 16 + tl16) * 8192;
#pragma unroll
  for (int dt = 0; dt < 4; ++dt)
#pragma unroll
    for (int r = 0; r < 4; ++r)
      cp[(w * 16 + kl * 4 + r) * 64 + dt * 16 + lm] = cacc[dt][r];
}

// ---------------- kRedCtx: merge 16 partials/bh with exp(m_t-MX), add eps terms ----------------
__global__ void kRedCtx(const float* __restrict__ ctxp, const float* __restrict__ ksump,
                        const float* __restrict__ vsp, unsigned short* __restrict__ CsG,
                        float* __restrict__ ksumG) {
  __shared__ __align__(16) float ctxL[16384];
  __shared__ float vsL[64];
  const int bh = blockIdx.x, t = threadIdx.x;   // 256 threads
  float f[16];
  {
    float mt[16], MX = -3e38f;
#pragma unroll
    for (int i = 0; i < 16; ++i) {
      mt[i] = ksumG[bh * 256 + 240 + i];   // packed maxes
      MX = fmaxf(MX, mt[i]);
    }
#pragma unroll
    for (int i = 0; i < 16; ++i) f[i] = __expf(mt[i] - MX);
  }
  __syncthreads();   // all threads read packed maxes before any ksumG writes
#pragma unroll
  for (int i = 0; i < 16; ++i) {
    int idx4 = t + i * 256;                 // float4 index; m = idx4>>4
    int mhi = (idx4 >> 11) & 1;             // m-half
    int loc = idx4 & 2047;
    float4 s = make_float4(0.f, 0.f, 0.f, 0.f);
#pragma unroll
    for (int tl = 0; tl < 8; ++tl) {
      float4 a = ((const float4*)(ctxp + (size_t)(bh * 16 + tl * 2 + mhi) * 8192))[loc];
      float sc = f[tl * 2 + mhi];
      s.x = fmaf(sc, a.x, s.x); s.y = fmaf(sc, a.y, s.y);
      s.z = fmaf(sc, a.z, s.z); s.w = fmaf(sc, a.w, s.w);
    }
    ((float4*)ctxL)[idx4] = s;
  }
  {
    int mhi = t >> 7, loc = t & 127;
    float ks = 0.f;
#pragma unroll
    for (int tl = 0; tl < 8; ++tl)
      ks = fmaf(f[tl * 2 + mhi], ksump[(size_t)(bh * 16 + tl * 2 + mhi) * 128 + loc], ks);
    ksumG[bh * 256 + t] = ks + FEPS * (float)BN;
  }
  if (t < 64) {
    float vs = 0.f;
#pragma unroll
    for (int tl = 0; tl < 8; ++tl) vs += vsp[(size_t)(bh * 8 + tl) * 64 + t];
    vsL[t] = vs;
  }
  __syncthreads();
#pragma unroll
  for (int i = 0; i < 8; ++i) {
    int slot = t + i * 256;   // [dt 4][s 8][lane 64]
    int l = slot & 63, s = (slot >> 6) & 7, dt = slot >> 9;
    int d = dt * 16 + (l & 15);
    int mb = s * 32 + (l >> 4) * 8;
    float ve = FEPS * vsL[d];
    unsigned short o[8];
#pragma unroll
    for (int j = 0; j < 8; ++j) o[j] = f2bf(ctxL[(mb + j) * 64 + d] + ve);
    *(uint4*)(CsG + (size_t)bh * 16384 + (size_t)slot * 8) =
        make_uint4(pk2(o[0], o[1]), pk2(o[2], o[3]), pk2(o[4], o[5]), pk2(o[6], o[7]));
  }
}

// ---------------- kOut: wave-private q pipeline -> output (unchanged) ----------------
__global__ void __launch_bounds__(512, 1)
kOut(const float* __restrict__ Qin, const unsigned short* __restrict__ BxG,
     const unsigned short* __restrict__ CsG, const float* __restrict__ ksumG,
     float* __restrict__ outp) {
  __shared__ __align__(16) unsigned short BxH[16384];    // 32 KB
  __shared__ __align__(16) unsigned short Ff[128 * 264]; // 67.6 KB q-features bf16
  __shared__ float den[128];                             // 1/denominator per row
  const int tid = threadIdx.x;
  int bh, tile;
  xcd_map<8>(bh, tile);
  const float* Qh = Qin + (size_t)bh * BN * DD;
  const unsigned short* CsB = CsG + (size_t)bh * 16384;
  const int w = tid >> 6, l = tid & 63, lm = l & 15, kl = l >> 4;
#pragma unroll
  for (int i = 0; i < 4; ++i)
    ((uint4*)BxH)[tid + i * 512] = ((const uint4*)BxG)[tid + i * 512];
  short8 cb[8];
#pragma unroll
  for (int s = 0; s < 8; ++s)
    cb[s] = *(const short8*)(CsB + (size_t)((((w >> 1) * 8 + s) * 64 + l) * 8));
  float kss[16];
#pragma unroll
  for (int j = 0; j < 16; ++j) kss[j] = ksumG[bh * 256 + j * 16 + lm];
  __syncthreads();   // BxH ready

  for (int ch = 0; ch < 8; ++ch) {
    const int r0 = tile * 1024 + ch * 128;
    const size_t rowoff = (size_t)(r0 + w * 16 + lm) * 64;
    float4 v0 = *(const float4*)(Qh + rowoff + kl * 8);
    float4 v1 = *(const float4*)(Qh + rowoff + kl * 8 + 4);
    float4 v2 = *(const float4*)(Qh + rowoff + 32 + kl * 8);
    float4 v3 = *(const float4*)(Qh + rowoff + 32 + kl * 8 + 4);
    half8 ah0, ah1, al0, al1;
    float sq = 0.f;
    {
      float x[16] = {v0.x, v0.y, v0.z, v0.w, v1.x, v1.y, v1.z, v1.w,
                     v2.x, v2.y, v2.z, v2.w, v3.x, v3.y, v3.z, v3.w};
#pragma unroll
      for (int e = 0; e < 16; ++e) {
        float y = x[e] * CNORM;
        _Float16 h = (_Float16)y;
        _Float16 lo = (_Float16)((y - (float)h) * 2048.0f);
        if (e < 8) { ah0[e] = h; al0[e] = lo; } else { ah1[e - 8] = h; al1[e - 8] = lo; }
        sq = fmaf(y, y, sq);
      }
      sq += __shfl_xor(sq, 16);
      sq += __shfl_xor(sq, 32);
    }
    const float diagv = 0.5f * sq;
    f32x4 accC[16];
#pragma unroll
    for (int j = 0; j < 16; ++j) {
      half8 b0 = *(const half8*)&BxH[((j * 2 + 0) * 64 + l) * 8];
      half8 b1 = *(const half8*)&BxH[((j * 2 + 1) * 64 + l) * 8];
      f32x4 acc0 = {0.f, 0.f, 0.f, 0.f}, acc1 = {0.f, 0.f, 0.f, 0.f};
      acc0 = __builtin_amdgcn_mfma_f32_16x16x32_f16(ah0, b0, acc0, 0, 0, 0);
      acc0 = __builtin_amdgcn_mfma_f32_16x16x32_f16(ah1, b1, acc0, 0, 0, 0);
      acc1 = __builtin_amdgcn_mfma_f32_16x16x32_f16(al0, b0, acc1, 0, 0, 0);
      acc1 = __builtin_amdgcn_mfma_f32_16x16x32_f16(al1, b1, acc1, 0, 0, 0);
#pragma unroll
      for (int r = 0; r < 4; ++r) accC[j][r] = fmaf(acc1[r], INV2048, acc0[r]);
    }
    float mrow[4];
#pragma unroll
    for (int r = 0; r < 4; ++r) {
      float m0 = accC[0][r];
#pragma unroll
      for (int j = 1; j < 16; ++j) m0 = fmaxf(m0, accC[j][r]);
      m0 = fmaxf(m0, __shfl_xor(m0, 1));
      m0 = fmaxf(m0, __shfl_xor(m0, 2));
      m0 = fmaxf(m0, __shfl_xor(m0, 4));
      m0 = fmaxf(m0, __shfl_xor(m0, 8));
      mrow[r] = m0;
    }
    float dgv[4], dnn[4] = {0.f, 0.f, 0.f, 0.f};
#pragma unroll
    for (int r = 0; r < 4; ++r)
      dgv[r] = __shfl(diagv, (l & 48) + kl * 4 + r) + mrow[r];
#pragma unroll
    for (int j = 0; j < 16; ++j) {
#pragma unroll
      for (int r = 0; r < 4; ++r) {
        float q = __expf(accC[j][r] - dgv[r]) + FEPS;
        unsigned short qh = f2bf(q);
        Ff[(w * 16 + kl * 4 + r) * 264 + j * 16 + lm] = qh;
        dnn[r] += bf2f(qh) * kss[j];
      }
    }
#pragma unroll
    for (int r = 0; r < 4; ++r) {
      dnn[r] += __shfl_xor(dnn[r], 1); dnn[r] += __shfl_xor(dnn[r], 2);
      dnn[r] += __shfl_xor(dnn[r], 4); dnn[r] += __shfl_xor(dnn[r], 8);
    }
    if (lm == 0) {
#pragma unroll
      for (int r = 0; r < 4; ++r) den[w * 16 + kl * 4 + r] = 1.0f / dnn[r];
    }
    __syncthreads();   // features + den ready for all waves
    const int prow = (w & 1) * 64, pd = (w >> 1) * 16;
    f32x4 oacc[4];
#pragma unroll
    for (int fr = 0; fr < 4; ++fr) oacc[fr] = f32x4{0.f, 0.f, 0.f, 0.f};
#pragma unroll
    for (int s = 0; s < 8; ++s) {
#pragma unroll
      for (int fr = 0; fr < 4; ++fr) {
        short8 af = *(const short8*)&Ff[(prow + fr * 16 + lm) * 264 + s * 32 + kl * 8];
        oacc[fr] = __builtin_amdgcn_mfma_f32_16x16x32_bf16(af, cb[s], oacc[fr], 0, 0, 0);
      }
    }
#pragma unroll
    for (int fr = 0; fr < 4; ++fr) {
#pragma unroll
      for (int r = 0; r < 4; ++r) {
        int n = prow + fr * 16 + kl * 4 + r;
        outp[((size_t)bh * BN + r0 + n) * 64 + pd + lm] = oacc[fr][r] * den[n];
      }
    }
    __syncthreads();   // p2 reads done before next chunk overwrites Ff
  }
}

extern "C" void kernel_launch(void* const* d_in, const int* in_sizes, int n_in,
                              void* d_out, int out_size, void* d_ws, size_t ws_size,
                              hipStream_t stream) {
  const float* Q    = (const float*)d_in[0];
  const float* K    = (const float*)d_in[1];
  const float* V    = (const float*)d_in[2];
  const float* mask = (const float*)d_in[3];
  const float* proj = (const float*)d_in[4];
  float* out = (float*)d_out;
  float* ws = (float*)d_ws;

  unsigned short* wBx = (unsigned short*)(ws + OFF_BX);
  unsigned short* wCs = (unsigned short*)(ws + OFF_CS);
  float* wKsump = ws + OFF_KSUMP;
  float* wKsumG = ws + OFF_KSUMG;
  float* wVsp   = ws + OFF_VSP;
  float* wCtxp  = ws + OFF_CTXP;

  kPrep<<<8, 256, 0, stream>>>(proj, wBx);
  kCtx<<<dim3(16, NHEADS), 512, 0, stream>>>(K, V, mask, wBx, wCtxp, wKsump, wKsumG, wVsp);
  kRedCtx<<<NHEADS, 256, 0, stream>>>(wCtxp, wKsump, wVsp, wCs, wKsumG);
  kOut<<<dim3(8, NHEADS), 512, 0, stream>>>(Q, wBx, wCs, wKsumG, out);
}

// Round 2
// 141.282 us; speedup vs baseline: 1.6072x; 1.6072x over previous
//
#include <hip/hip_runtime.h>

// Performer (FAVOR+) self-attention. B=4 H=8 N=8192 D=64 M=256.
// Round 12: kCtx v2 — de-spilled wave-private pipeline.
//  - Round-11 spilled (WRITE_SIZE 190 MB): online block-max forced accC[8]
//    (32 regs) live across p1 + vv/kv/frags > 128-reg cap.
//  - Fix: NO online max. Accumulate unscaled exp(xd-diag) partials (f32 range
//    is ample: xd<=~15 -> sums <=~1e10); per-wave max tracked in ONE register
//    for the eps-term semantics; kRedCtx applies a single exp(-MX).
//  - p1 fused per-j: 4 MFMAs -> combine -> exp -> bf16 -> Fs. accC liveness
//    32 -> 4. Mask loaded as float4 post-p1 (no msks LDS).
//  - 512 blocks x 512 thr, ~74 KB LDS, launch_bounds(512,4) -> 2 blocks/CU.
// kPrep -> kCtx -> kRedCtx -> kOut

typedef __attribute__((ext_vector_type(8))) short short8;
typedef __attribute__((ext_vector_type(8))) _Float16 half8;
typedef __attribute__((ext_vector_type(4))) float f32x4;

namespace {
constexpr int BN = 8192, DD = 64, MM = 256, NHEADS = 32;
constexpr float CNORM = 0.35355339059327373f;  // D^-0.25
constexpr float FEPS  = 1e-4f;
constexpr float INV2048 = 4.8828125e-4f;

// workspace layout in floats (total 4,555,008 f = 18.22 MB, unchanged)
constexpr size_t OFF_BX    = 0;         // 16384 ushort = 8192 f
constexpr size_t OFF_CS    = 8192;      // 32*16384 ushort -> ends 270336
constexpr size_t OFF_KSUMP = 270336;    // 32*16*128 = 65536 -> 335872
constexpr size_t OFF_KSUMG = 335872;    // 32*256 = 8192 -> 344064 (mx packed @ +240..255/bh)
constexpr size_t OFF_VSP   = 344320;    // 32*8*64 = 16384 -> 360704
constexpr size_t OFF_CTXP  = 360704;    // 32*16*8192 = 4194304 -> 4555008
}

__device__ __forceinline__ unsigned short f2bf(float f) {
  unsigned u = __float_as_uint(f);
  u += 0x7fffu + ((u >> 16) & 1u);
  return (unsigned short)(u >> 16);
}
__device__ __forceinline__ float bf2f(unsigned short h) {
  return __uint_as_float(((unsigned)h) << 16);
}
__device__ __forceinline__ unsigned pk2(unsigned short a, unsigned short b) {
  return (unsigned)a | ((unsigned)b << 16);
}
__device__ __forceinline__ unsigned short f2h(float f) {
  _Float16 h = (_Float16)f;
  return __builtin_bit_cast(unsigned short, h);
}
__device__ __forceinline__ float h2f(unsigned short u) {
  return (float)__builtin_bit_cast(_Float16, u);
}

// XCD swizzle: linear id -> (bh, tile); each XCD owns 4 consecutive heads.
template <int T>
__device__ __forceinline__ void xcd_map(int& bh, int& tile) {
  int id = blockIdx.y * T + blockIdx.x;
  int xcd = id & 7, s = id >> 3;
  bh = xcd * 4 + s / T;
  tile = s % T;
}

// ---------------- kPrep: proj -> single-f16 B-fragment stream (32 KB) ----------------
// BxG[mt 16][kb 2][lane 64][8 f16]; kb = K-half (d 0-31 / 32-63).
__global__ void kPrep(const float* __restrict__ proj, unsigned short* __restrict__ BxG) {
  int s = blockIdx.x * 256 + threadIdx.x;   // 0..2047
  int l = s & 63, kb = (s >> 6) & 1, mt = s >> 7;
  int n = mt * 16 + (l & 15);
  int k0 = kb * 32 + (l >> 4) * 8;
  unsigned short o[8];
#pragma unroll
  for (int j = 0; j < 8; ++j) o[j] = f2h(proj[n * 64 + k0 + j]);
  *(uint4*)(BxG + (size_t)s * 8) =
      make_uint4(pk2(o[0], o[1]), pk2(o[2], o[3]), pk2(o[4], o[5]), pk2(o[6], o[7]));
}

// ---------------- kCtx: unscaled k-feature pipeline -> ctx/ksum partials + max ----------------
// Block = (bh, tile, mh): 1024 rows (8 chunks x 128), m-half mh*128..+128.
// Per chunk: wave w owns 16 K rows (A-frags in regs from global), p1 fused
// with features (exp(xd-diag), no max), p2: ctx += k'^T V. 2 barriers/chunk.
__global__ void __launch_bounds__(512, 4)
kCtx(const float* __restrict__ Kin, const float* __restrict__ Vin,
     const float* __restrict__ mask, const unsigned short* __restrict__ BxG,
     float* __restrict__ ctxp, float* __restrict__ ksump,
     float* __restrict__ mxg, float* __restrict__ vsp) {
  __shared__ __align__(16) unsigned short BxH[8192];      // 16 KB (this m-half of proj)
  __shared__ __align__(16) unsigned short Fs[128 * 140];  // 35 KB features [m][n], stride 140
  __shared__ __align__(16) unsigned short VF[16 * 64 * 8];// 16 KB [ks4][dt4][lane64][8] bf16
  __shared__ float wmax[8];
  __shared__ float ksred[1024];
  __shared__ float vred[512];
  const int tid = threadIdx.x;
  int bh, tl16;
  xcd_map<16>(bh, tl16);
  const int tile = tl16 >> 1, mh = tl16 & 1;
  const int b = bh >> 3;
  const float* Kh = Kin + (size_t)bh * BN * DD;
  const float* Vh = Vin + (size_t)bh * BN * DD;
  const float* mrow = mask + (size_t)b * BN;
#pragma unroll
  for (int i = 0; i < 2; ++i)
    ((uint4*)BxH)[tid + i * 512] = ((const uint4*)BxG)[mh * 1024 + tid + i * 512];
  const int w = tid >> 6, l = tid & 63, lm = l & 15, kl = l >> 4;
  const int lmv = tid & 15, klnv = (tid >> 4) & 3, dtv = (tid >> 6) & 3, ksv0 = tid >> 8;

  f32x4 cacc[4];
#pragma unroll
  for (int dt = 0; dt < 4; ++dt) cacc[dt] = f32x4{0.f, 0.f, 0.f, 0.f};
  float kspart[8] = {0.f, 0.f, 0.f, 0.f, 0.f, 0.f, 0.f, 0.f};
  float wm = -3e38f, vsum = 0.f;

  const int rbase = tile * 1024;
  // peel: K regs for chunk 0
  float4 kv0, kv1, kv2, kv3;
  float mskK;
  {
    const float* rp = Kh + (size_t)(rbase + w * 16 + lm) * 64 + kl * 8;
    kv0 = *(const float4*)rp;        kv1 = *(const float4*)(rp + 4);
    kv2 = *(const float4*)(rp + 32); kv3 = *(const float4*)(rp + 36);
    mskK = mrow[rbase + w * 16 + lm];
  }
  __syncthreads();   // BxH ready

  for (int ch = 0; ch < 8; ++ch) {
    const int r0 = rbase + ch * 128;
    // ---- convert own K row regs -> hi/lo f16 A-frags + diag ----
    half8 ah0, ah1, al0, al1;
    float diagv;
    {
      float scale = CNORM * mskK;
      float x[16] = {kv0.x, kv0.y, kv0.z, kv0.w, kv1.x, kv1.y, kv1.z, kv1.w,
                     kv2.x, kv2.y, kv2.z, kv2.w, kv3.x, kv3.y, kv3.z, kv3.w};
      float sq = 0.f;
#pragma unroll
      for (int e = 0; e < 16; ++e) {
        float y = x[e] * scale;
        _Float16 h = (_Float16)y;
        _Float16 lo = (_Float16)((y - (float)h) * 2048.0f);
        if (e < 8) { ah0[e] = h; al0[e] = lo; } else { ah1[e - 8] = h; al1[e - 8] = lo; }
        sq = fmaf(y, y, sq);
      }
      sq += __shfl_xor(sq, 16);
      sq += __shfl_xor(sq, 32);
      diagv = 0.5f * sq;
    }
    // ---- prefetch next chunk's K rows ----
    {
      const int nr = rbase + ((ch + 1) & 7) * 128 + w * 16 + lm;
      const float* rp = Kh + (size_t)nr * 64 + kl * 8;
      kv0 = *(const float4*)rp;        kv1 = *(const float4*)(rp + 4);
      kv2 = *(const float4*)(rp + 32); kv3 = *(const float4*)(rp + 36);
      mskK = mrow[nr];
    }
    // ---- issue V loads (consumed after p1) ----
    float vv[16];
#pragma unroll
    for (int h = 0; h < 2; ++h) {
      int nb = (ksv0 * 2 + h) * 32 + klnv * 8;
#pragma unroll
      for (int j = 0; j < 8; ++j)
        vv[h * 8 + j] = Vh[(size_t)(r0 + nb + j) * 64 + dtv * 16 + lmv];
    }
    // ---- p1 fused with features: per j, 4 MFMAs -> exp -> bf16 -> Fs ----
    float dgv[4];
#pragma unroll
    for (int r = 0; r < 4; ++r)
      dgv[r] = __shfl(diagv, (l & 48) + kl * 4 + r);
#pragma unroll
    for (int j = 0; j < 8; ++j) {
      half8 b0 = *(const half8*)&BxH[((j * 2 + 0) * 64 + l) * 8];
      half8 b1 = *(const half8*)&BxH[((j * 2 + 1) * 64 + l) * 8];
      f32x4 a0 = {0.f, 0.f, 0.f, 0.f}, a1 = {0.f, 0.f, 0.f, 0.f};
      a0 = __builtin_amdgcn_mfma_f32_16x16x32_f16(ah0, b0, a0, 0, 0, 0);
      a0 = __builtin_amdgcn_mfma_f32_16x16x32_f16(ah1, b1, a0, 0, 0, 0);
      a1 = __builtin_amdgcn_mfma_f32_16x16x32_f16(al0, b0, a1, 0, 0, 0);
      a1 = __builtin_amdgcn_mfma_f32_16x16x32_f16(al1, b1, a1, 0, 0, 0);
      float x0 = fmaf(a1[0], INV2048, a0[0]);
      float x1 = fmaf(a1[1], INV2048, a0[1]);
      float x2 = fmaf(a1[2], INV2048, a0[2]);
      float x3 = fmaf(a1[3], INV2048, a0[3]);
      wm = fmaxf(wm, fmaxf(fmaxf(x0, x1), fmaxf(x2, x3)));
      float f0 = __expf(x0 - dgv[0]);
      float f1 = __expf(x1 - dgv[1]);
      float f2 = __expf(x2 - dgv[2]);
      float f3 = __expf(x3 - dgv[3]);
      kspart[j] += f0 + f1 + f2 + f3;
      *(uint2*)&Fs[(j * 16 + lm) * 140 + w * 16 + kl * 4] =
          make_uint2(pk2(f2bf(f0), f2bf(f1)), pk2(f2bf(f2), f2bf(f3)));
    }
    // ---- V -> VF (bf16 frag-linear) + masked V row-sum; mask via float4 ----
#pragma unroll
    for (int h = 0; h < 2; ++h) {
      int ks = ksv0 * 2 + h;
      int nb = ks * 32 + klnv * 8;
      float4 m0 = *(const float4*)&mrow[r0 + nb];
      float4 m1 = *(const float4*)&mrow[r0 + nb + 4];
      float mk[8] = {m0.x, m0.y, m0.z, m0.w, m1.x, m1.y, m1.z, m1.w};
      unsigned short o[8];
#pragma unroll
      for (int j = 0; j < 8; ++j) {
        float vmv = vv[h * 8 + j] * mk[j];
        o[j] = f2bf(vmv);
        vsum += vmv;
      }
      *(uint4*)&VF[((ks * 4 + dtv) * 64 + klnv * 16 + lmv) * 8] =
          make_uint4(pk2(o[0], o[1]), pk2(o[2], o[3]), pk2(o[4], o[5]), pk2(o[6], o[7]));
    }
    __syncthreads();   // barrier 1: Fs + VF ready
    // ---- p2: ctx[m][d] += k'^T V; wave w owns m-rows w*16..+16 ----
#pragma unroll
    for (int ks = 0; ks < 4; ++ks) {
      union { short8 v; uint2 u[2]; } af;
      const int ab = (w * 16 + lm) * 140 + ks * 32 + kl * 8;
      af.u[0] = *(const uint2*)&Fs[ab];
      af.u[1] = *(const uint2*)&Fs[ab + 4];
#pragma unroll
      for (int dt = 0; dt < 4; ++dt) {
        short8 vb = *(const short8*)&VF[((ks * 4 + dt) * 64 + l) * 8];
        cacc[dt] = __builtin_amdgcn_mfma_f32_16x16x32_bf16(af.v, vb, cacc[dt], 0, 0, 0);
      }
    }
    __syncthreads();   // barrier 2: p2 reads done before next chunk's writes
  }
  // ---- epilogue: ksum partials, vsum, max, ctx partials ----
#pragma unroll
  for (int j = 0; j < 8; ++j) {
    kspart[j] += __shfl_xor(kspart[j], 16);
    kspart[j] += __shfl_xor(kspart[j], 32);
  }
  if (l < 16) {
#pragma unroll
    for (int j = 0; j < 8; ++j) ksred[(j * 16 + l) * 8 + w] = kspart[j];
  }
  {
    wm = fmaxf(wm, __shfl_xor(wm, 1));  wm = fmaxf(wm, __shfl_xor(wm, 2));
    wm = fmaxf(wm, __shfl_xor(wm, 4));  wm = fmaxf(wm, __shfl_xor(wm, 8));
    wm = fmaxf(wm, __shfl_xor(wm, 16)); wm = fmaxf(wm, __shfl_xor(wm, 32));
    if (l == 0) wmax[w] = wm;
  }
  vred[tid] = vsum;
  __syncthreads();
  if (tid < 128) {
    float s = 0.f;
#pragma unroll
    for (int k = 0; k < 8; ++k) s += ksred[tid * 8 + k];
    ksump[(size_t)(bh * 16 + tl16) * 128 + tid] = s;
  }
  if (mh == 0 && tid < 64) {
    float vs = 0.f;
#pragma unroll
    for (int k = 0; k < 8; ++k)
      vs += vred[(k >> 2) * 256 + (tid >> 4) * 64 + (k & 3) * 16 + (tid & 15)];
    vsp[(size_t)(bh * 8 + tile) * 64 + tid] = vs;
  }
  if (tid == 0) {
    float bm = wmax[0];
#pragma unroll
    for (int i = 1; i < 8; ++i) bm = fmaxf(bm, wmax[i]);
    mxg[bh * 256 + 240 + tl16] = bm;   // packed into ksumG tail
  }
  float* cp = ctxp + (size_t)(bh * 16 + tl16) * 8192;
#pragma unroll
  for (int dt = 0; dt < 4; ++dt)
#pragma unroll
    for (int r = 0; r < 4; ++r)
      cp[(w * 16 + kl * 4 + r) * 64 + dt * 16 + lm] = cacc[dt][r];
}

// ---------------- kRedCtx: sum 16 unscaled partials/bh, scale exp(-MX), eps terms ----------------
__global__ void kRedCtx(const float* __restrict__ ctxp, const float* __restrict__ ksump,
                        const float* __restrict__ vsp, unsigned short* __restrict__ CsG,
                        float* __restrict__ ksumG) {
  __shared__ __align__(16) float ctxL[16384];
  __shared__ float vsL[64];
  const int bh = blockIdx.x, t = threadIdx.x;   // 256 threads
  float MX = -3e38f;
#pragma unroll
  for (int i = 0; i < 16; ++i) MX = fmaxf(MX, ksumG[bh * 256 + 240 + i]);  // packed maxes
  const float fsc = __expf(-MX);
  __syncthreads();   // all threads read packed maxes before any ksumG writes
#pragma unroll
  for (int i = 0; i < 16; ++i) {
    int idx4 = t + i * 256;                 // float4 index; m = idx4>>4
    int mhi = (idx4 >> 11) & 1;             // m-half
    int loc = idx4 & 2047;
    float4 s = make_float4(0.f, 0.f, 0.f, 0.f);
#pragma unroll
    for (int tl = 0; tl < 8; ++tl) {
      float4 a = ((const float4*)(ctxp + (size_t)(bh * 16 + tl * 2 + mhi) * 8192))[loc];
      s.x += a.x; s.y += a.y; s.z += a.z; s.w += a.w;
    }
    s.x *= fsc; s.y *= fsc; s.z *= fsc; s.w *= fsc;
    ((float4*)ctxL)[idx4] = s;
  }
  {
    int mhi = t >> 7, loc = t & 127;
    float ks = 0.f;
#pragma unroll
    for (int tl = 0; tl < 8; ++tl)
      ks += ksump[(size_t)(bh * 16 + tl * 2 + mhi) * 128 + loc];
    ksumG[bh * 256 + t] = fsc * ks + FEPS * (float)BN;
  }
  if (t < 64) {
    float vs = 0.f;
#pragma unroll
    for (int tl = 0; tl < 8; ++tl) vs += vsp[(size_t)(bh * 8 + tl) * 64 + t];
    vsL[t] = vs;
  }
  __syncthreads();
#pragma unroll
  for (int i = 0; i < 8; ++i) {
    int slot = t + i * 256;   // [dt 4][s 8][lane 64]
    int l = slot & 63, s = (slot >> 6) & 7, dt = slot >> 9;
    int d = dt * 16 + (l & 15);
    int mb = s * 32 + (l >> 4) * 8;
    float ve = FEPS * vsL[d];
    unsigned short o[8];
#pragma unroll
    for (int j = 0; j < 8; ++j) o[j] = f2bf(ctxL[(mb + j) * 64 + d] + ve);
    *(uint4*)(CsG + (size_t)bh * 16384 + (size_t)slot * 8) =
        make_uint4(pk2(o[0], o[1]), pk2(o[2], o[3]), pk2(o[4], o[5]), pk2(o[6], o[7]));
  }
}

// ---------------- kOut: wave-private q pipeline -> output (unchanged) ----------------
__global__ void __launch_bounds__(512, 1)
kOut(const float* __restrict__ Qin, const unsigned short* __restrict__ BxG,
     const unsigned short* __restrict__ CsG, const float* __restrict__ ksumG,
     float* __restrict__ outp) {
  __shared__ __align__(16) unsigned short BxH[16384];    // 32 KB
  __shared__ __align__(16) unsigned short Ff[128 * 264]; // 67.6 KB q-features bf16
  __shared__ float den[128];                             // 1/denominator per row
  const int tid = threadIdx.x;
  int bh, tile;
  xcd_map<8>(bh, tile);
  const float* Qh = Qin + (size_t)bh * BN * DD;
  const unsigned short* CsB = CsG + (size_t)bh * 16384;
  const int w = tid >> 6, l = tid & 63, lm = l & 15, kl = l >> 4;
#pragma unroll
  for (int i = 0; i < 4; ++i)
    ((uint4*)BxH)[tid + i * 512] = ((const uint4*)BxG)[tid + i * 512];
  short8 cb[8];
#pragma unroll
  for (int s = 0; s < 8; ++s)
    cb[s] = *(const short8*)(CsB + (size_t)((((w >> 1) * 8 + s) * 64 + l) * 8));
  float kss[16];
#pragma unroll
  for (int j = 0; j < 16; ++j) kss[j] = ksumG[bh * 256 + j * 16 + lm];
  __syncthreads();   // BxH ready

  for (int ch = 0; ch < 8; ++ch) {
    const int r0 = tile * 1024 + ch * 128;
    const size_t rowoff = (size_t)(r0 + w * 16 + lm) * 64;
    float4 v0 = *(const float4*)(Qh + rowoff + kl * 8);
    float4 v1 = *(const float4*)(Qh + rowoff + kl * 8 + 4);
    float4 v2 = *(const float4*)(Qh + rowoff + 32 + kl * 8);
    float4 v3 = *(const float4*)(Qh + rowoff + 32 + kl * 8 + 4);
    half8 ah0, ah1, al0, al1;
    float sq = 0.f;
    {
      float x[16] = {v0.x, v0.y, v0.z, v0.w, v1.x, v1.y, v1.z, v1.w,
                     v2.x, v2.y, v2.z, v2.w, v3.x, v3.y, v3.z, v3.w};
#pragma unroll
      for (int e = 0; e < 16; ++e) {
        float y = x[e] * CNORM;
        _Float16 h = (_Float16)y;
        _Float16 lo = (_Float16)((y - (float)h) * 2048.0f);
        if (e < 8) { ah0[e] = h; al0[e] = lo; } else { ah1[e - 8] = h; al1[e - 8] = lo; }
        sq = fmaf(y, y, sq);
      }
      sq += __shfl_xor(sq, 16);
      sq += __shfl_xor(sq, 32);
    }
    const float diagv = 0.5f * sq;
    f32x4 accC[16];
#pragma unroll
    for (int j = 0; j < 16; ++j) {
      half8 b0 = *(const half8*)&BxH[((j * 2 + 0) * 64 + l) * 8];
      half8 b1 = *(const half8*)&BxH[((j * 2 + 1) * 64 + l) * 8];
      f32x4 acc0 = {0.f, 0.f, 0.f, 0.f}, acc1 = {0.f, 0.f, 0.f, 0.f};
      acc0 = __builtin_amdgcn_mfma_f32_16x16x32_f16(ah0, b0, acc0, 0, 0, 0);
      acc0 = __builtin_amdgcn_mfma_f32_16x16x32_f16(ah1, b1, acc0, 0, 0, 0);
      acc1 = __builtin_amdgcn_mfma_f32_16x16x32_f16(al0, b0, acc1, 0, 0, 0);
      acc1 = __builtin_amdgcn_mfma_f32_16x16x32_f16(al1, b1, acc1, 0, 0, 0);
#pragma unroll
      for (int r = 0; r < 4; ++r) accC[j][r] = fmaf(acc1[r], INV2048, acc0[r]);
    }
    float mrow[4];
#pragma unroll
    for (int r = 0; r < 4; ++r) {
      float m0 = accC[0][r];
#pragma unroll
      for (int j = 1; j < 16; ++j) m0 = fmaxf(m0, accC[j][r]);
      m0 = fmaxf(m0, __shfl_xor(m0, 1));
      m0 = fmaxf(m0, __shfl_xor(m0, 2));
      m0 = fmaxf(m0, __shfl_xor(m0, 4));
      m0 = fmaxf(m0, __shfl_xor(m0, 8));
      mrow[r] = m0;
    }
    float dgv[4], dnn[4] = {0.f, 0.f, 0.f, 0.f};
#pragma unroll
    for (int r = 0; r < 4; ++r)
      dgv[r] = __shfl(diagv, (l & 48) + kl * 4 + r) + mrow[r];
#pragma unroll
    for (int j = 0; j < 16; ++j) {
#pragma unroll
      for (int r = 0; r < 4; ++r) {
        float q = __expf(accC[j][r] - dgv[r]) + FEPS;
        unsigned short qh = f2bf(q);
        Ff[(w * 16 + kl * 4 + r) * 264 + j * 16 + lm] = qh;
        dnn[r] += bf2f(qh) * kss[j];
      }
    }
#pragma unroll
    for (int r = 0; r < 4; ++r) {
      dnn[r] += __shfl_xor(dnn[r], 1); dnn[r] += __shfl_xor(dnn[r], 2);
      dnn[r] += __shfl_xor(dnn[r], 4); dnn[r] += __shfl_xor(dnn[r], 8);
    }
    if (lm == 0) {
#pragma unroll
      for (int r = 0; r < 4; ++r) den[w * 16 + kl * 4 + r] = 1.0f / dnn[r];
    }
    __syncthreads();   // features + den ready for all waves
    const int prow = (w & 1) * 64, pd = (w >> 1) * 16;
    f32x4 oacc[4];
#pragma unroll
    for (int fr = 0; fr < 4; ++fr) oacc[fr] = f32x4{0.f, 0.f, 0.f, 0.f};
#pragma unroll
    for (int s = 0; s < 8; ++s) {
#pragma unroll
      for (int fr = 0; fr < 4; ++fr) {
        short8 af = *(const short8*)&Ff[(prow + fr * 16 + lm) * 264 + s * 32 + kl * 8];
        oacc[fr] = __builtin_amdgcn_mfma_f32_16x16x32_bf16(af, cb[s], oacc[fr], 0, 0, 0);
      }
    }
#pragma unroll
    for (int fr = 0; fr < 4; ++fr) {
#pragma unroll
      for (int r = 0; r < 4; ++r) {
        int n = prow + fr * 16 + kl * 4 + r;
        outp[((size_t)bh * BN + r0 + n) * 64 + pd + lm] = oacc[fr][r] * den[n];
      }
    }
    __syncthreads();   // p2 reads done before next chunk overwrites Ff
  }
}

extern "C" void kernel_launch(void* const* d_in, const int* in_sizes, int n_in,
                              void* d_out, int out_size, void* d_ws, size_t ws_size,
                              hipStream_t stream) {
  const float* Q    = (const float*)d_in[0];
  const float* K    = (const float*)d_in[1];
  const float* V    = (const float*)d_in[2];
  const float* mask = (const float*)d_in[3];
  const float* proj = (const float*)d_in[4];
  float* out = (float*)d_out;
  float* ws = (float*)d_ws;

  unsigned short* wBx = (unsigned short*)(ws + OFF_BX);
  unsigned short* wCs = (unsigned short*)(ws + OFF_CS);
  float* wKsump = ws + OFF_KSUMP;
  float* wKsumG = ws + OFF_KSUMG;
  float* wVsp   = ws + OFF_VSP;
  float* wCtxp  = ws + OFF_CTXP;

  kPrep<<<8, 256, 0, stream>>>(proj, wBx);
  kCtx<<<dim3(16, NHEADS), 512, 0, stream>>>(K, V, mask, wBx, wCtxp, wKsump, wKsumG, wVsp);
  kRedCtx<<<NHEADS, 256, 0, stream>>>(wCtxp, wKsump, wVsp, wCs, wKsumG);
  kOut<<<dim3(8, NHEADS), 512, 0, stream>>>(Q, wBx, wCs, wKsumG, out);
}